// Round 4
// baseline (101.090 us; speedup 1.0000x reference)
//
#include <hip/hip_runtime.h>
#include <hip/hip_fp16.h>

// COO SpMM, rows sorted: out[r] = sum_{e: rows[e]==r} vals[e] * embeds[cols[e]]
// N=50000, E=800000, D=64 fp32.
//
// R9: persistent-wave spmm. R8 showed halving gather issue count only bought
// 4us -> spmm is dominated by short-block overhead (12.5k blocks, sub-us of
// work per wave) + clamp-group waste, not issue count or bandwidth.
// Now: 2048 blocks (8/CU), each wave owns a contiguous ~7-row chunk:
//  - row_ptr: one new load per row (s = prev t), sequential
//  - bulk edges via clamp-free paired groups; <=2 clamped tail groups
//  - cols/vals nontemporal (stream-once; keep L2 for embeds gather)
// Lane map unchanged from R8: slot=lane>>3 (8 edges/group), f8=lane&7
// (16B of fp16 row per lane; one gather instr = 8 rows x 128B = 1KiB).
// fp16 embeds staged in d_ws (fp32 accum, absmax 0.0625 << 0.29).

#define D_FEAT 64
#define BLOCK 256
#define PERSIST_BLOCKS 2048

typedef float f32x4 __attribute__((ext_vector_type(4)));

// Fused setup: blocks [0, nb_rp) build row_ptr, blocks [nb_rp, ...) do f32->f16.
__global__ __launch_bounds__(BLOCK) void setup_fused(
    const int* __restrict__ rows, int* __restrict__ row_ptr,
    const float* __restrict__ embeds, __half* __restrict__ embeds_h,
    int n_nodes, int n_edges, int n4, int nb_rp)
{
    if ((int)blockIdx.x < nb_rp) {
        const int e = blockIdx.x * BLOCK + threadIdx.x;
        if (e >= n_edges) return;
        const int r  = rows[e];
        const int rp = (e == 0) ? -1 : rows[e - 1];
        for (int v = rp + 1; v <= r; ++v) row_ptr[v] = e;
        if (e == n_edges - 1)
            for (int v = r + 1; v <= n_nodes; ++v) row_ptr[v] = n_edges;
    } else {
        const int i = ((int)blockIdx.x - nb_rp) * BLOCK + (int)threadIdx.x;
        if (i >= n4) return;
        const float4 x = ((const float4*)embeds)[i];
        __half2 a = __floats2half2_rn(x.x, x.y);
        __half2 b = __floats2half2_rn(x.z, x.w);
        ((__half2*)embeds_h)[2 * i]     = a;
        ((__half2*)embeds_h)[2 * i + 1] = b;
    }
}

__global__ __launch_bounds__(BLOCK) void spmm_persist(
    const int* __restrict__ row_ptr,
    const int* __restrict__ cols,
    const float* __restrict__ vals,
    const __half* __restrict__ embeds_h,
    float* __restrict__ out,
    int n_nodes)
{
    const int wave_g = (int)(blockIdx.x * (BLOCK / 64) + (threadIdx.x >> 6));
    const int total_waves = PERSIST_BLOCKS * (BLOCK / 64);          // 8192
    const int chunk = (n_nodes + total_waves - 1) / total_waves;    // ~7
    const int r0 = wave_g * chunk;
    if (r0 >= n_nodes) return;
    const int r1 = (r0 + chunk < n_nodes) ? r0 + chunk : n_nodes;

    const int lane = (int)(threadIdx.x & 63u);
    const int slot = lane >> 3;   // edge slot 0..7
    const int f8   = lane & 7;    // 16B chunk 0..7
    const char* eb   = (const char*)embeds_h;
    const int   foff = f8 << 4;

// clamp-free group: all 8 edges guaranteed < t
#define GROUP_NC(EBASE)                                                        \
    {                                                                          \
        const int ik = (EBASE) + slot;                                         \
        const int ck = __builtin_nontemporal_load(cols + ik);                  \
        const float vk = __builtin_nontemporal_load(vals + ik);                \
        const uint4 p = *(const uint4*)(eb + (((unsigned)ck << 7) + foff));    \
        float2 q0 = __half22float2(*(const __half2*)&p.x);                     \
        float2 q1 = __half22float2(*(const __half2*)&p.y);                     \
        float2 q2 = __half22float2(*(const __half2*)&p.z);                     \
        float2 q3 = __half22float2(*(const __half2*)&p.w);                     \
        acc[0] = fmaf(vk, q0.x, acc[0]); acc[1] = fmaf(vk, q0.y, acc[1]);      \
        acc[2] = fmaf(vk, q1.x, acc[2]); acc[3] = fmaf(vk, q1.y, acc[3]);      \
        acc[4] = fmaf(vk, q2.x, acc[4]); acc[5] = fmaf(vk, q2.y, acc[5]);      \
        acc[6] = fmaf(vk, q3.x, acc[6]); acc[7] = fmaf(vk, q3.y, acc[7]);      \
    }

// clamped group: tail, some edges may be >= t
#define GROUP_C(EBASE, TM1)                                                    \
    {                                                                          \
        const int ik = (EBASE) + slot;                                         \
        const int jk = ik < (TM1) ? ik : (TM1);                                \
        const int ck = __builtin_nontemporal_load(cols + jk);                  \
        float vk = __builtin_nontemporal_load(vals + jk);                      \
        if (ik > (TM1)) vk = 0.f;                                              \
        const uint4 p = *(const uint4*)(eb + (((unsigned)ck << 7) + foff));    \
        float2 q0 = __half22float2(*(const __half2*)&p.x);                     \
        float2 q1 = __half22float2(*(const __half2*)&p.y);                     \
        float2 q2 = __half22float2(*(const __half2*)&p.z);                     \
        float2 q3 = __half22float2(*(const __half2*)&p.w);                     \
        acc[0] = fmaf(vk, q0.x, acc[0]); acc[1] = fmaf(vk, q0.y, acc[1]);      \
        acc[2] = fmaf(vk, q1.x, acc[2]); acc[3] = fmaf(vk, q1.y, acc[3]);      \
        acc[4] = fmaf(vk, q2.x, acc[4]); acc[5] = fmaf(vk, q2.y, acc[5]);      \
        acc[6] = fmaf(vk, q3.x, acc[6]); acc[7] = fmaf(vk, q3.y, acc[7]);      \
    }

    int s = row_ptr[r0];
    for (int r = r0; r < r1; ++r) {
        const int t = row_ptr[r + 1];
        float acc[8] = {0.f, 0.f, 0.f, 0.f, 0.f, 0.f, 0.f, 0.f};

        if (s < t) {
            const int tm1 = t - 1;
            int e = s;
            // full pairs, no clamp needed (e+16 <= t-1 ensures e..e+15 < t)
            for (; e + 16 < t; e += 16) {
                GROUP_NC(e)
                GROUP_NC(e + 8)
            }
            // tail: 1..16 edges left
            GROUP_C(e, tm1)
            if (e + 8 < t) GROUP_C(e + 8, tm1)
        }

#pragma unroll
        for (int i = 0; i < 8; ++i) {
            acc[i] += __shfl_xor(acc[i], 8, 64);
            acc[i] += __shfl_xor(acc[i], 16, 64);
            acc[i] += __shfl_xor(acc[i], 32, 64);
        }

        if (lane < 8) {
            f32x4 v0, v1;
            v0.x = acc[0]; v0.y = acc[1]; v0.z = acc[2]; v0.w = acc[3];
            v1.x = acc[4]; v1.y = acc[5]; v1.z = acc[6]; v1.w = acc[7];
            f32x4* po = (f32x4*)(out + (size_t)r * D_FEAT + (f8 << 3));
            __builtin_nontemporal_store(v0, po);
            __builtin_nontemporal_store(v1, po + 1);
        }
        s = t;
    }
#undef GROUP_NC
#undef GROUP_C
}

extern "C" void kernel_launch(void* const* d_in, const int* in_sizes, int n_in,
                              void* d_out, int out_size, void* d_ws, size_t ws_size,
                              hipStream_t stream) {
    const int*   rows   = (const int*)d_in[0];
    const int*   cols   = (const int*)d_in[1];
    const float* vals   = (const float*)d_in[2];
    const float* embeds = (const float*)d_in[3];
    float*       out    = (float*)d_out;

    const int n_edges = in_sizes[0];
    const int n_nodes = out_size / D_FEAT;
    const int n_feat_total = n_nodes * D_FEAT;   // 3.2M

    int*    row_ptr  = (int*)d_ws;                               // 50001 ints
    __half* embeds_h = (__half*)((char*)d_ws + (1 << 18));       // 6.4 MB @ 256KB offset

    {
        const int n4 = n_feat_total / 4;
        const int nb_rp  = (n_edges + BLOCK - 1) / BLOCK;
        const int nb_cvt = (n4 + BLOCK - 1) / BLOCK;
        setup_fused<<<nb_rp + nb_cvt, BLOCK, 0, stream>>>(
            rows, row_ptr, embeds, embeds_h, n_nodes, n_edges, n4, nb_rp);
    }
    {
        spmm_persist<<<PERSIST_BLOCKS, BLOCK, 0, stream>>>(
            row_ptr, cols, vals, embeds_h, out, n_nodes);
    }
}

// Round 6
// 97.809 us; speedup vs baseline: 1.0336x; 1.0336x over previous
//
#include <hip/hip_runtime.h>
#include <hip/hip_fp16.h>

// COO SpMM, rows sorted: out[r] = sum_{e: rows[e]==r} vals[e] * embeds[cols[e]]
// N=50000, E=800000, D=64 fp32.
//
// R11 = R10 resubmitted (previous bench died to container infra, kernel
// never ran). Theory: spmm is gather-LATENCY-bound; R8 (50k waves, 2
// gathers in flight) = 94us; R9 (8.2k waves, serial rows) = 101us ->
// wave count and per-wave independent gathers are the levers. Two rows
// per wave, INTERLEAVED: 25k waves, majority path (deg<=24 both rows,
// P~0.96) issues 6 independent gather groups straight-line, tripling
// in-flight lines per wave vs R8. Reduction+store once per wave.
// Lane map: slot=lane>>3 (8 edges/group), f8=lane&7 (16B of the 128B
// fp16 row per lane; one gather instr = 8 rows x 128B = 1KiB).
// cols/vals nontemporal (stream-once, keep L2 for embeds gather).
// fp16 embeds staged in d_ws (fp32 accum, absmax 0.0625 << 0.29).

#define D_FEAT 64
#define BLOCK 256

typedef float f32x4 __attribute__((ext_vector_type(4)));

// Fused setup: blocks [0, nb_rp) build row_ptr, blocks [nb_rp, ...) do f32->f16.
__global__ __launch_bounds__(BLOCK) void setup_fused(
    const int* __restrict__ rows, int* __restrict__ row_ptr,
    const float* __restrict__ embeds, __half* __restrict__ embeds_h,
    int n_nodes, int n_edges, int n4, int nb_rp)
{
    if ((int)blockIdx.x < nb_rp) {
        const int e = blockIdx.x * BLOCK + threadIdx.x;
        if (e >= n_edges) return;
        const int r  = rows[e];
        const int rp = (e == 0) ? -1 : rows[e - 1];
        for (int v = rp + 1; v <= r; ++v) row_ptr[v] = e;
        if (e == n_edges - 1)
            for (int v = r + 1; v <= n_nodes; ++v) row_ptr[v] = n_edges;
    } else {
        const int i = ((int)blockIdx.x - nb_rp) * BLOCK + (int)threadIdx.x;
        if (i >= n4) return;
        const float4 x = ((const float4*)embeds)[i];
        __half2 a = __floats2half2_rn(x.x, x.y);
        __half2 b = __floats2half2_rn(x.z, x.w);
        ((__half2*)embeds_h)[2 * i]     = a;
        ((__half2*)embeds_h)[2 * i + 1] = b;
    }
}

// One wave handles rows 2w and 2w+1, interleaved.
__global__ __launch_bounds__(BLOCK) void spmm_pair(
    const int* __restrict__ row_ptr,
    const int* __restrict__ cols,
    const float* __restrict__ vals,
    const __half* __restrict__ embeds_h,
    float* __restrict__ out,
    int n_nodes)
{
    const int pair = (int)((blockIdx.x * (unsigned)BLOCK + threadIdx.x) >> 6);
    const int rA = pair * 2;
    if (rA >= n_nodes) return;
    const int rB = rA + 1;
    const bool hasB = rB < n_nodes;

    const int lane = (int)(threadIdx.x & 63u);
    const int slot = lane >> 3;   // edge slot 0..7
    const int f8   = lane & 7;    // 16B chunk 0..7
    const char* eb   = (const char*)embeds_h;
    const int   foff = f8 << 4;

    // row_ptr[rA], row_ptr[rA+1], row_ptr[rA+2]; middle shared by A end / B start
    const int sA = row_ptr[rA];
    const int tA = row_ptr[rA + 1];
    const int sB = tA;
    const int tB = hasB ? row_ptr[rB + 1] : tA;

    const int degA = tA - sA;
    const int degB = tB - sB;
    const int tm1A = tA - 1;
    const int tm1B = tB - 1;

    float accA[8] = {0.f, 0.f, 0.f, 0.f, 0.f, 0.f, 0.f, 0.f};
    float accB[8] = {0.f, 0.f, 0.f, 0.f, 0.f, 0.f, 0.f, 0.f};

// clamped 8-edge group accumulating into ACC; safe for any deg >= 1
#define GROUP(EBASE, TM1, ACC)                                                 \
    {                                                                          \
        const int ik = (EBASE) + slot;                                         \
        const int jk = ik < (TM1) ? ik : (TM1);                                \
        const int ck = __builtin_nontemporal_load(cols + jk);                  \
        float vk = __builtin_nontemporal_load(vals + jk);                      \
        if (ik > (TM1)) vk = 0.f;                                              \
        const uint4 p = *(const uint4*)(eb + (((unsigned)ck << 7) + foff));    \
        float2 q0 = __half22float2(*(const __half2*)&p.x);                     \
        float2 q1 = __half22float2(*(const __half2*)&p.y);                     \
        float2 q2 = __half22float2(*(const __half2*)&p.z);                     \
        float2 q3 = __half22float2(*(const __half2*)&p.w);                     \
        ACC[0] = fmaf(vk, q0.x, ACC[0]); ACC[1] = fmaf(vk, q0.y, ACC[1]);      \
        ACC[2] = fmaf(vk, q1.x, ACC[2]); ACC[3] = fmaf(vk, q1.y, ACC[3]);      \
        ACC[4] = fmaf(vk, q2.x, ACC[4]); ACC[5] = fmaf(vk, q2.y, ACC[5]);      \
        ACC[6] = fmaf(vk, q3.x, ACC[6]); ACC[7] = fmaf(vk, q3.y, ACC[7]);      \
    }

    if (degA > 0 && degA <= 24 && degB > 0 && degB <= 24) {
        // majority path (P ~ 0.96): 6 independent gathers, no loop carried dep
        GROUP(sA,      tm1A, accA)
        GROUP(sB,      tm1B, accB)
        GROUP(sA + 8,  tm1A, accA)
        GROUP(sB + 8,  tm1B, accB)
        GROUP(sA + 16, tm1A, accA)
        GROUP(sB + 16, tm1B, accB)
    } else {
        if (degA > 0)
            for (int e = sA; e < tA; e += 8) GROUP(e, tm1A, accA)
        if (degB > 0)
            for (int e = sB; e < tB; e += 8) GROUP(e, tm1B, accB)
    }
#undef GROUP

    // fold the 8 edge slots for both rows (xor 8, 16, 32)
#pragma unroll
    for (int i = 0; i < 8; ++i) {
        accA[i] += __shfl_xor(accA[i], 8, 64);
        accB[i] += __shfl_xor(accB[i], 8, 64);
        accA[i] += __shfl_xor(accA[i], 16, 64);
        accB[i] += __shfl_xor(accB[i], 16, 64);
        accA[i] += __shfl_xor(accA[i], 32, 64);
        accB[i] += __shfl_xor(accB[i], 32, 64);
    }

    // lanes 0..7 store row A, lanes 8..15 store row B (folded values valid on
    // every lane; f8 = lane&7 picks the 32B feature chunk)
    if (lane < 8) {
        f32x4 v0, v1;
        v0.x = accA[0]; v0.y = accA[1]; v0.z = accA[2]; v0.w = accA[3];
        v1.x = accA[4]; v1.y = accA[5]; v1.z = accA[6]; v1.w = accA[7];
        f32x4* po = (f32x4*)(out + (size_t)rA * D_FEAT + (f8 << 3));
        __builtin_nontemporal_store(v0, po);
        __builtin_nontemporal_store(v1, po + 1);
    } else if (lane < 16 && hasB) {
        f32x4 v0, v1;
        v0.x = accB[0]; v0.y = accB[1]; v0.z = accB[2]; v0.w = accB[3];
        v1.x = accB[4]; v1.y = accB[5]; v1.z = accB[6]; v1.w = accB[7];
        f32x4* po = (f32x4*)(out + (size_t)rB * D_FEAT + (f8 << 3));
        __builtin_nontemporal_store(v0, po);
        __builtin_nontemporal_store(v1, po + 1);
    }
}

extern "C" void kernel_launch(void* const* d_in, const int* in_sizes, int n_in,
                              void* d_out, int out_size, void* d_ws, size_t ws_size,
                              hipStream_t stream) {
    const int*   rows   = (const int*)d_in[0];
    const int*   cols   = (const int*)d_in[1];
    const float* vals   = (const float*)d_in[2];
    const float* embeds = (const float*)d_in[3];
    float*       out    = (float*)d_out;

    const int n_edges = in_sizes[0];
    const int n_nodes = out_size / D_FEAT;
    const int n_feat_total = n_nodes * D_FEAT;   // 3.2M

    int*    row_ptr  = (int*)d_ws;                               // 50001 ints
    __half* embeds_h = (__half*)((char*)d_ws + (1 << 18));       // 6.4 MB @ 256KB offset

    {
        const int n4 = n_feat_total / 4;
        const int nb_rp  = (n_edges + BLOCK - 1) / BLOCK;
        const int nb_cvt = (n4 + BLOCK - 1) / BLOCK;
        setup_fused<<<nb_rp + nb_cvt, BLOCK, 0, stream>>>(
            rows, row_ptr, embeds, embeds_h, n_nodes, n_edges, n4, nb_rp);
    }
    {
        const int n_pairs = (n_nodes + 1) / 2;                   // 25000
        const int waves_per_block = BLOCK / 64;
        const int nblocks = (n_pairs + waves_per_block - 1) / waves_per_block;
        spmm_pair<<<nblocks, BLOCK, 0, stream>>>(
            row_ptr, cols, vals, embeds_h, out, n_nodes);
    }
}